// Round 3
// baseline (121.049 us; speedup 1.0000x reference)
//
#include <hip/hip_runtime.h>
#include <math.h>

#define HH 256
#define WW 256
#define NG 714
#define NROWS 768          // padded rows; pad rows always culled
#define NGP4 716           // s_tz padded for float4 rank loop
#define FOCALF 128.0f
#define EPS2D_F 0.3f
#define ALPHA_MIN_F (1.0f/255.0f)
#define CAM_T_F 8.0f
#define LOG2E_F 1.4426950408889634f
#define PR 12              // floats/row: [mx,my,A2n,B2n][C2n,K,cr,cg][cb,e,f,thr]
#define T_EPS 0.003f       // in-wave early-break bound (error <= eps per channel)

// Kernel 1: projection + conic + stable depth rank + scatter into sorted rows.
// Conic stored NEGATED, prefolded with log2(e); K = log2(op) folded additively:
// sg = A2n*dx^2 + B2n*dx*dy + C2n*dy^2 + K  ->  alpha = exp2(sg) = op*exp(-sigma).
// Cull fields: e = C-B^2/4A, f = A-B^2/4C (positive conic, >=0);
// gaussian irrelevant for a box iff max(e*dymin^2, f*dxmin^2) > thr = log2(255)+K
// (then alpha < 1/255 for EVERY pixel in the box -> reference zeroes it: EXACT cull).
__global__ __launch_bounds__(256) void gs_prep(
    const float* __restrict__ means, const float* __restrict__ quats,
    const float* __restrict__ scales, const float* __restrict__ opacities,
    const float* __restrict__ rgbs, float* __restrict__ params)
{
    __shared__ float s_tz[NGP4];
    const int lane = threadIdx.x;
    const int i = blockIdx.x * 256 + lane;

    for (int j = lane; j < NGP4; j += 256)
        s_tz[j] = (j < NG) ? (means[3*j+2] + CAM_T_F) : INFINITY;
    __syncthreads();

    if (i >= NROWS) return;
    if (i >= NG) {                      // pad rows: always culled (0 > thr=-1)
        float4* row = (float4*)(params + i*PR);
        row[0] = make_float4(0.f,0.f,0.f,0.f);
        row[1] = make_float4(0.f,0.f,0.f,0.f);
        row[2] = make_float4(0.f,0.f,0.f,-1.f);
        return;
    }

    float m0 = means[i*3+0], m1 = means[i*3+1];
    float tz = s_tz[i];
    float qw = quats[i*4+0], qx = quats[i*4+1], qy = quats[i*4+2], qz = quats[i*4+3];
    float qn = rsqrtf(qw*qw + qx*qx + qy*qy + qz*qz);
    qw*=qn; qx*=qn; qy*=qn; qz*=qn;
    float sx = scales[i*3+0], sy = scales[i*3+1], sz = scales[i*3+2];
    float s0 = sx*sx, s1 = sy*sy, s2 = sz*sz;
    float R00 = 1.f-2.f*(qy*qy+qz*qz), R01 = 2.f*(qx*qy-qw*qz), R02 = 2.f*(qx*qz+qw*qy);
    float R10 = 2.f*(qx*qy+qw*qz),     R11 = 1.f-2.f*(qx*qx+qz*qz), R12 = 2.f*(qy*qz-qw*qx);
    float R20 = 2.f*(qx*qz-qw*qy),     R21 = 2.f*(qy*qz+qw*qx),     R22 = 1.f-2.f*(qx*qx+qy*qy);
    float S00 = R00*R00*s0 + R01*R01*s1 + R02*R02*s2;
    float S01 = R00*R10*s0 + R01*R11*s1 + R02*R12*s2;
    float S02 = R00*R20*s0 + R01*R21*s1 + R02*R22*s2;
    float S11 = R10*R10*s0 + R11*R11*s1 + R12*R12*s2;
    float S12 = R10*R20*s0 + R11*R21*s1 + R12*R22*s2;
    float S22 = R20*R20*s0 + R21*R21*s1 + R22*R22*s2;
    float inv = 1.f/tz;
    float mx = FOCALF*m0*inv + 0.5f*WW;
    float my = FOCALF*m1*inv + 0.5f*HH;
    float j0 = FOCALF*inv;
    float j2 = -FOCALF*m0*inv*inv;
    float j5 = -FOCALF*m1*inv*inv;
    float a = j0*j0*S00 + 2.f*j0*j2*S02 + j2*j2*S22 + EPS2D_F;
    float b = j0*(j0*S01 + j2*S12) + j5*(j0*S02 + j2*S22);
    float c = j0*j0*S11 + 2.f*j0*j5*S12 + j5*j5*S22 + EPS2D_F;
    float det = a*c - b*b;
    float idet = 1.f/det;
    float hA = 0.5f*c*idet*LOG2E_F;      // positive conic terms (log2-scaled)
    float Bc = -b*idet*LOG2E_F;
    float hC = 0.5f*a*idet*LOG2E_F;
    float e  = hC - Bc*Bc/(4.f*hA);      // min over dx of sigma' = e*dy^2
    float f  = hA - Bc*Bc/(4.f*hC);      // min over dy of sigma' = f*dx^2
    float op = 1.f/(1.f+__expf(-opacities[i]));
    float K  = log2f(op);                // folded into exponent
    float thr = log2f(255.f) + K;        // cull iff bound > thr
    float cr = 1.f/(1.f+__expf(-rgbs[i*3+0]));
    float cg = 1.f/(1.f+__expf(-rgbs[i*3+1]));
    float cb = 1.f/(1.f+__expf(-rgbs[i*3+2]));

    const float4* t4 = (const float4*)s_tz;
    int rank = 0;
    #pragma unroll 4
    for (int jj = 0; jj < NGP4/4; ++jj) {
        float4 v = t4[jj];
        int j = 4*jj;
        rank += (v.x < tz) || (v.x == tz && (j+0) < i);
        rank += (v.y < tz) || (v.y == tz && (j+1) < i);
        rank += (v.z < tz) || (v.z == tz && (j+2) < i);
        rank += (v.w < tz) || (v.w == tz && (j+3) < i);
    }

    float4* row = (float4*)(params + rank*PR);
    row[0] = make_float4(mx, my, -hA, -Bc);
    row[1] = make_float4(-hC, K, cr, cg);
    row[2] = make_float4(cb, e, f, thr);
}

// Kernel 2: cull-once-then-compact compositing. 256 blocks = 256 tiles
// (16x16 px); block = 256 threads = 4 waves.
// Phase A: stage all 768 sorted param rows into LDS (coalesced float4).
// Phase B: every thread culls 3 rows for THIS tile; __ballot builds a
//   768-bit hit mask in depth order; popcount prefix -> compacted hit list.
// Phase C: 4 waves (one per SIMD: no VALU contention, key for hot tiles)
//   composite contiguous quarters of the hit list; rows read from LDS at
//   wave-uniform addresses (broadcast, conflict-free); register pipeline
//   distance 2; register-only ballot early break (bounded error < T_EPS).
// Phase D: in-block fold of the 4 depth partials (associative) -> out.
// No scan waste (cold tiles exit after Phase B), no cross-block traffic,
// no fences (round-1 lesson).
__global__ __launch_bounds__(256) void gs_composite(
    const float* __restrict__ params, float* __restrict__ out)
{
    __shared__ float4 sp[NROWS*3];              // 36 KB staged rows
    __shared__ unsigned long long masks[12];    // 768-bit hit mask
    __shared__ unsigned int offs[13];
    __shared__ unsigned short list[NROWS+16];   // compacted hit list + pads
    __shared__ float4 part[4][4][64];           // 16 KB depth partials

    const int tx = threadIdx.x;                 // 0..63
    const int wv = __builtin_amdgcn_readfirstlane((int)threadIdx.y);  // 0..3
    const int t  = (wv << 6) | tx;              // 0..255
    const int tile = blockIdx.x;
    const int x0 = (tile & 15) * 16;
    const int y0 = (tile >> 4) * 16;

    // Phase A: params -> LDS, fully coalesced (2304 float4 / 256 threads = 9 each)
    {
        const float4* g = (const float4*)params;
        #pragma unroll
        for (int j = 0; j < 9; ++j) sp[t + 256*j] = g[t + 256*j];
    }
    __syncthreads();

    // Phase B: per-row tile cull -> masks -> prefix -> compacted list
    const float xc   = (float)x0 + 8.0f;        // box center, half-span 7.5
    const float ycen = (float)y0 + 8.0f;
    bool hit[3];
    #pragma unroll
    for (int k = 0; k < 3; ++k) {
        const int r = (k << 8) | t;             // row r; mask word = r>>6 = 4k+wv
        float4 r0 = sp[3*r];
        float4 r2 = sp[3*r+2];
        float dymin = fmaxf(fabsf(ycen - r0.y) - 7.5f, 0.f);
        float dxmin = fmaxf(fabsf(xc   - r0.x) - 7.5f, 0.f);
        float m = fmaxf(r2.y*dymin*dymin, r2.z*dxmin*dxmin);
        hit[k] = !(m > r2.w);                   // exact cull (pads: 0 > -1 -> culled)
        unsigned long long bm = __ballot(hit[k]);
        if (tx == 0) masks[(k << 2) | wv] = bm;
    }
    __syncthreads();
    if (t == 0) {
        unsigned int s = 0;
        #pragma unroll
        for (int j = 0; j < 12; ++j) { offs[j] = s; s += __popcll(masks[j]); }
        offs[12] = s;
    }
    __syncthreads();
    #pragma unroll
    for (int k = 0; k < 3; ++k) {
        if (hit[k]) {
            const int j = (k << 2) | wv;
            unsigned long long m = masks[j];
            const int pos = offs[j] + __popcll(m & ((1ull << tx) - 1ull));
            list[pos] = (unsigned short)((k << 8) | t);
        }
    }
    const unsigned int H = offs[12];
    if (t < 16) list[H + t] = 0;                // pads: load-safe, never computed
    __syncthreads();

    // Phase C: 4 waves composite contiguous depth quarters of the hit list
    const float px = (float)(x0 + (tx & 15)) + 0.5f;
    const float yb = (float)(y0 + ((tx >> 4) << 2)) + 0.5f;   // 4-row bundle base

    float T0=1.f,r0=0.f,g0=0.f,bl0=0.f;
    float T1=1.f,r1=0.f,g1=0.f,bl1=0.f;
    float T2=1.f,r2=0.f,g2=0.f,bl2=0.f;
    float T3=1.f,r3=0.f,g3=0.f,bl3=0.f;

    const unsigned int chunk = (H + 3u) >> 2;
    const unsigned int start = wv * chunk;
    const unsigned int end   = (start + chunk > H) ? H : (start + chunk);

    if (start < end) {
        int ia = list[start], ib = list[start+1];
        float4 a0=sp[3*ia], a1=sp[3*ia+1], a2=sp[3*ia+2];
        float4 b0=sp[3*ib], b1=sp[3*ib+1], b2=sp[3*ib+2];
        int inx = list[start+2];
        for (unsigned int i = start; i < end; ++i) {
            float4 c0=sp[3*inx], c1=sp[3*inx+1], c2=sp[3*inx+2];
            inx = list[i+3];                    // pads cover reads past end

            float dy0 = yb - a0.y;
            float dy1 = dy0 + 1.f, dy2 = dy0 + 2.f, dy3 = dy0 + 3.f;
            float dx  = px - a0.x;
            float axx = fmaf(a0.z*dx, dx, a1.y);    // A2n*dx^2 + K
            float bdx = a0.w*dx;

            float sg0 = fmaf(bdx, dy0, fmaf(a1.x*dy0, dy0, axx));
            float al0 = __builtin_amdgcn_exp2f(sg0);
            al0 = (al0 < ALPHA_MIN_F) ? 0.f : al0;
            float w0 = T0*al0; r0 += w0*a1.z; g0 += w0*a1.w; bl0 += w0*a2.x; T0 -= w0;

            float sg1 = fmaf(bdx, dy1, fmaf(a1.x*dy1, dy1, axx));
            float al1 = __builtin_amdgcn_exp2f(sg1);
            al1 = (al1 < ALPHA_MIN_F) ? 0.f : al1;
            float w1 = T1*al1; r1 += w1*a1.z; g1 += w1*a1.w; bl1 += w1*a2.x; T1 -= w1;

            float sg2 = fmaf(bdx, dy2, fmaf(a1.x*dy2, dy2, axx));
            float al2 = __builtin_amdgcn_exp2f(sg2);
            al2 = (al2 < ALPHA_MIN_F) ? 0.f : al2;
            float w2 = T2*al2; r2 += w2*a1.z; g2 += w2*a1.w; bl2 += w2*a2.x; T2 -= w2;

            float sg3 = fmaf(bdx, dy3, fmaf(a1.x*dy3, dy3, axx));
            float al3 = __builtin_amdgcn_exp2f(sg3);
            al3 = (al3 < ALPHA_MIN_F) ? 0.f : al3;
            float w3 = T3*al3; r3 += w3*a1.z; g3 += w3*a1.w; bl3 += w3*a2.x; T3 -= w3;

            // register-only early break (local T bounds true T from above)
            float tmax = fmaxf(fmaxf(T0,T1), fmaxf(T2,T3));
            if (__ballot(tmax > T_EPS) == 0ull) break;

            a0=b0; a1=b1; a2=b2;
            b0=c0; b1=c1; b2=c2;
        }
    }

    part[wv][0][tx] = make_float4(r0,g0,bl0,T0);
    part[wv][1][tx] = make_float4(r1,g1,bl1,T1);
    part[wv][2][tx] = make_float4(r2,g2,bl2,T2);
    part[wv][3][tx] = make_float4(r3,g3,bl3,T3);
    __syncthreads();

    // Phase D: wave k folds pixel-row k of each thread's 4-row bundle, in order
    {
        const int k = wv;
        float R=0.f,G=0.f,B=0.f,T=1.f;
        #pragma unroll
        for (int s = 0; s < 4; ++s) {
            float4 v = part[s][k][tx];
            R += T*v.x; G += T*v.y; B += T*v.z; T *= v.w;
        }
        const int y = y0 + ((tx >> 4) << 2) + k;
        const int x = x0 + (tx & 15);
        float* o = out + (y*WW + x)*3;
        o[0] = R; o[1] = G; o[2] = B;
    }
}

extern "C" void kernel_launch(void* const* d_in, const int* in_sizes, int n_in,
                              void* d_out, int out_size, void* d_ws, size_t ws_size,
                              hipStream_t stream) {
    // d_in: 0=coords (unused by reference), 1=means, 2=quats, 3=scales, 4=opacities, 5=rgbs
    const float* means  = (const float*)d_in[1];
    const float* quats  = (const float*)d_in[2];
    const float* scales = (const float*)d_in[3];
    const float* opac   = (const float*)d_in[4];
    const float* rgbs   = (const float*)d_in[5];

    float* params = (float*)d_ws;                   // NROWS*PR floats = 36 KB

    gs_prep<<<3, 256, 0, stream>>>(means, quats, scales, opac, rgbs, params);
    gs_composite<<<256, dim3(64,4), 0, stream>>>(params, (float*)d_out);
}

// Round 4
// 103.467 us; speedup vs baseline: 1.1699x; 1.1699x over previous
//
#include <hip/hip_runtime.h>
#include <math.h>

#define HH 256
#define WW 256
#define NG 714
#define NROWS 768          // padded to 3x256 prep grid; pad rows always culled
#define NGP4 716           // s_tz padded for float4 rank loop
#define SEG 23             // rows per wave sub-segment (32 segs x 23 = 736 >= 714)
#define NQTR 8             // depth quarters per tile (8 x 4 waves = 32 segments)
#define FOCALF 128.0f
#define EPS2D_F 0.3f
#define ALPHA_MIN_F (1.0f/255.0f)
#define CAM_T_F 8.0f
#define LOG2E_F 1.4426950408889634f
#define PR 12              // floats/row: [mx,my,A2n,B2n][C2n,K,cr,cg][cb,e,f,thr]
#define T_EPS 0.003f       // in-wave early-break bound (error <= eps per channel)
#define NPX 65536

// Kernel 1: projection + conic + stable depth rank + scatter into sorted rows.
// Conic stored NEGATED, prefolded with log2(e); K = log2(op) folded additively:
// sg = A2n*dx^2 + B2n*dx*dy + C2n*dy^2 + K  ->  alpha = exp2(sg) = op*exp(-sigma).
// Cull fields: e = C-B^2/4A, f = A-B^2/4C (positive conic, >=0);
// gaussian irrelevant for a box iff max(e*dymin^2, f*dxmin^2) > thr = log2(255)+K
// (then alpha < 1/255 for EVERY pixel in the box -> reference zeroes it: EXACT cull).
__global__ __launch_bounds__(256) void gs_prep(
    const float* __restrict__ means, const float* __restrict__ quats,
    const float* __restrict__ scales, const float* __restrict__ opacities,
    const float* __restrict__ rgbs, float* __restrict__ params)
{
    __shared__ float s_tz[NGP4];
    const int lane = threadIdx.x;
    const int i = blockIdx.x * 256 + lane;

    for (int j = lane; j < NGP4; j += 256)
        s_tz[j] = (j < NG) ? (means[3*j+2] + CAM_T_F) : INFINITY;
    __syncthreads();

    if (i >= NROWS) return;
    if (i >= NG) {                      // pad rows: always culled (0 > thr=-1)
        float4* row = (float4*)(params + i*PR);
        row[0] = make_float4(0.f,0.f,0.f,0.f);
        row[1] = make_float4(0.f,0.f,0.f,0.f);
        row[2] = make_float4(0.f,0.f,0.f,-1.f);
        return;
    }

    float m0 = means[i*3+0], m1 = means[i*3+1];
    float tz = s_tz[i];
    float qw = quats[i*4+0], qx = quats[i*4+1], qy = quats[i*4+2], qz = quats[i*4+3];
    float qn = rsqrtf(qw*qw + qx*qx + qy*qy + qz*qz);
    qw*=qn; qx*=qn; qy*=qn; qz*=qn;
    float sx = scales[i*3+0], sy = scales[i*3+1], sz = scales[i*3+2];
    float s0 = sx*sx, s1 = sy*sy, s2 = sz*sz;
    float R00 = 1.f-2.f*(qy*qy+qz*qz), R01 = 2.f*(qx*qy-qw*qz), R02 = 2.f*(qx*qz+qw*qy);
    float R10 = 2.f*(qx*qy+qw*qz),     R11 = 1.f-2.f*(qx*qx+qz*qz), R12 = 2.f*(qy*qz-qw*qx);
    float R20 = 2.f*(qx*qz-qw*qy),     R21 = 2.f*(qy*qz+qw*qx),     R22 = 1.f-2.f*(qx*qx+qy*qy);
    float S00 = R00*R00*s0 + R01*R01*s1 + R02*R02*s2;
    float S01 = R00*R10*s0 + R01*R11*s1 + R02*R12*s2;
    float S02 = R00*R20*s0 + R01*R21*s1 + R02*R22*s2;
    float S11 = R10*R10*s0 + R11*R11*s1 + R12*R12*s2;
    float S12 = R10*R20*s0 + R11*R21*s1 + R12*R22*s2;
    float S22 = R20*R20*s0 + R21*R21*s1 + R22*R22*s2;
    float inv = 1.f/tz;
    float mx = FOCALF*m0*inv + 0.5f*WW;
    float my = FOCALF*m1*inv + 0.5f*HH;
    float j0 = FOCALF*inv;
    float j2 = -FOCALF*m0*inv*inv;
    float j5 = -FOCALF*m1*inv*inv;
    float a = j0*j0*S00 + 2.f*j0*j2*S02 + j2*j2*S22 + EPS2D_F;
    float b = j0*(j0*S01 + j2*S12) + j5*(j0*S02 + j2*S22);
    float c = j0*j0*S11 + 2.f*j0*j5*S12 + j5*j5*S22 + EPS2D_F;
    float det = a*c - b*b;
    float idet = 1.f/det;
    float hA = 0.5f*c*idet*LOG2E_F;      // positive conic terms (log2-scaled)
    float Bc = -b*idet*LOG2E_F;
    float hC = 0.5f*a*idet*LOG2E_F;
    float e  = hC - Bc*Bc/(4.f*hA);      // min over dx of sigma' = e*dy^2
    float f  = hA - Bc*Bc/(4.f*hC);      // min over dy of sigma' = f*dx^2
    float op = 1.f/(1.f+__expf(-opacities[i]));
    float K  = log2f(op);                // folded into exponent
    float thr = log2f(255.f) + K;        // cull iff bound > thr
    float cr = 1.f/(1.f+__expf(-rgbs[i*3+0]));
    float cg = 1.f/(1.f+__expf(-rgbs[i*3+1]));
    float cb = 1.f/(1.f+__expf(-rgbs[i*3+2]));

    const float4* t4 = (const float4*)s_tz;
    int rank = 0;
    #pragma unroll 4
    for (int jj = 0; jj < NGP4/4; ++jj) {
        float4 v = t4[jj];
        int j = 4*jj;
        rank += (v.x < tz) || (v.x == tz && (j+0) < i);
        rank += (v.y < tz) || (v.y == tz && (j+1) < i);
        rank += (v.z < tz) || (v.z == tz && (j+2) < i);
        rank += (v.w < tz) || (v.w == tz && (j+3) < i);
    }

    float4* row = (float4*)(params + rank*PR);
    row[0] = make_float4(mx, my, -hA, -Bc);
    row[1] = make_float4(-hC, K, cr, cg);
    row[2] = make_float4(cb, e, f, thr);
}

// Kernel 2: compositing, block-level depth split for load balance.
// 2048 blocks = 256 tiles (16x16 px) x 8 depth eighths; blockIdx = tile*8+qtr
// so a hot tile's slices land on consecutive dispatch slots -> distinct CUs.
// 8/CU avg: hot-tile slices co-schedule with cold ones (round-3 lesson: never
// 1 block/CU). Block = 4 waves = 4 sub-segments (23 rows) of the slice;
// thread = 4 contiguous rows at one x. Distance-2 register prefetch; square
// cull box (7.5,7.5) wave-uniform; register-only ballot early break (bounded
// error < T_EPS). SEG=23 (vs 46) halves the serial path of non-breaking
// straggler waves (edge tiles), which bound the kernel at low tail occupancy.
// In-block LDS reduce -> one float4 (R,G,B,T) slice-partial per pixel.
__global__ __launch_bounds__(256, 4) void gs_composite(
    const float* __restrict__ params, float4* __restrict__ qpart)
{
    __shared__ float4 part[4][4][64];       // [wave][row k][tx] = 16 KB
    const int tx = threadIdx.x;             // 0..63
    const int wv = __builtin_amdgcn_readfirstlane((int)threadIdx.y);
    const int tile = blockIdx.x >> 3;
    const int qtr  = blockIdx.x & 7;
    const int x0 = (tile & 15) * 16;
    const int y0 = (tile >> 4) * 16;
    const float px   = (float)(x0 + (tx & 15)) + 0.5f;
    const float yb   = (float)(y0 + ((tx >> 4) << 2)) + 0.5f;   // row-group base
    const float xc   = (float)x0 + 8.0f;    // box center, half-span 7.5
    const float ycen = (float)y0 + 8.0f;
    const int n0 = (qtr*4 + wv) * SEG;      // wave's sub-segment start

    const float4* p = ((const float4*)params) + 3*n0;
    float4 a0=p[0], a1=p[1], a2=p[2];
    float4 b0=p[3], b1=p[4], b2=p[5];

    float T0=1.f,r0=0.f,g0=0.f,bl0=0.f;
    float T1=1.f,r1=0.f,g1=0.f,bl1=0.f;
    float T2=1.f,r2=0.f,g2=0.f,bl2=0.f;
    float T3=1.f,r3=0.f,g3=0.f,bl3=0.f;

    for (int n = 0; n < SEG; ++n) {
        float4 c0=p[6], c1=p[7], c2=p[8]; p += 3;   // prefetch n+2 (pads cover tail)
        float dymin = fmaxf(fabsf(ycen - a0.y) - 7.5f, 0.f);
        float dxmin = fmaxf(fabsf(xc - a0.x) - 7.5f, 0.f);
        float m = fmaxf(a2.y*dymin*dymin, a2.z*dxmin*dxmin);
        if (!(m > a2.w)) {                          // wave-uniform branch
            float dy0 = yb - a0.y;
            float dy1 = dy0 + 1.f, dy2 = dy0 + 2.f, dy3 = dy0 + 3.f;
            float dx  = px - a0.x;
            float axx = fmaf(a0.z*dx, dx, a1.y);    // A2n*dx^2 + K
            float bdx = a0.w*dx;

            float sg0 = fmaf(bdx, dy0, fmaf(a1.x*dy0, dy0, axx));
            float al0 = __builtin_amdgcn_exp2f(sg0);
            al0 = (al0 < ALPHA_MIN_F) ? 0.f : al0;
            float w0 = T0*al0; r0 += w0*a1.z; g0 += w0*a1.w; bl0 += w0*a2.x; T0 -= w0;

            float sg1 = fmaf(bdx, dy1, fmaf(a1.x*dy1, dy1, axx));
            float al1 = __builtin_amdgcn_exp2f(sg1);
            al1 = (al1 < ALPHA_MIN_F) ? 0.f : al1;
            float w1 = T1*al1; r1 += w1*a1.z; g1 += w1*a1.w; bl1 += w1*a2.x; T1 -= w1;

            float sg2 = fmaf(bdx, dy2, fmaf(a1.x*dy2, dy2, axx));
            float al2 = __builtin_amdgcn_exp2f(sg2);
            al2 = (al2 < ALPHA_MIN_F) ? 0.f : al2;
            float w2 = T2*al2; r2 += w2*a1.z; g2 += w2*a1.w; bl2 += w2*a2.x; T2 -= w2;

            float sg3 = fmaf(bdx, dy3, fmaf(a1.x*dy3, dy3, axx));
            float al3 = __builtin_amdgcn_exp2f(sg3);
            al3 = (al3 < ALPHA_MIN_F) ? 0.f : al3;
            float w3 = T3*al3; r3 += w3*a1.z; g3 += w3*a1.w; bl3 += w3*a2.x; T3 -= w3;

            // register-only early break (local T bounds true T from above)
            float tmax = fmaxf(fmaxf(T0,T1), fmaxf(T2,T3));
            if (__ballot(tmax > T_EPS) == 0ull) break;
        }
        a0=b0; a1=b1; a2=b2;
        b0=c0; b1=c1; b2=c2;
    }

    part[wv][0][tx] = make_float4(r0,g0,bl0,T0);
    part[wv][1][tx] = make_float4(r1,g1,bl1,T1);
    part[wv][2][tx] = make_float4(r2,g2,bl2,T2);
    part[wv][3][tx] = make_float4(r3,g3,bl3,T3);
    __syncthreads();

    {   // wave k reduces pixel-row k of each thread's 4-row bundle, in depth order
        const int k = wv;
        float R=0.f,G=0.f,B=0.f,T=1.f;
        #pragma unroll
        for (int s = 0; s < 4; ++s) {
            float4 v = part[s][k][tx];
            R += T*v.x; G += T*v.y; B += T*v.z; T *= v.w;
        }
        const int y = y0 + ((tx >> 4) << 2) + k;
        const int x = x0 + (tx & 15);
        qpart[qtr*NPX + y*WW + x] = make_float4(R,G,B,T);
    }
}

// Kernel 3: fold the 8 depth-slice partials in order.
__global__ __launch_bounds__(256) void gs_combine(
    const float4* __restrict__ qpart, float* __restrict__ out)
{
    const int px = blockIdx.x*256 + threadIdx.x;
    float R=0.f, G=0.f, B=0.f, T=1.f;
    #pragma unroll
    for (int q = 0; q < NQTR; ++q) {
        float4 p = qpart[q*NPX + px];
        R += T*p.x; G += T*p.y; B += T*p.z; T *= p.w;
    }
    out[px*3+0] = R;
    out[px*3+1] = G;
    out[px*3+2] = B;
}

extern "C" void kernel_launch(void* const* d_in, const int* in_sizes, int n_in,
                              void* d_out, int out_size, void* d_ws, size_t ws_size,
                              hipStream_t stream) {
    // d_in: 0=coords (unused by reference), 1=means, 2=quats, 3=scales, 4=opacities, 5=rgbs
    const float* means  = (const float*)d_in[1];
    const float* quats  = (const float*)d_in[2];
    const float* scales = (const float*)d_in[3];
    const float* opac   = (const float*)d_in[4];
    const float* rgbs   = (const float*)d_in[5];

    char* ws = (char*)d_ws;
    float*  params = (float*)ws;                    // NROWS*PR floats = 36 KB
    float4* qpart  = (float4*)(ws + (64<<10));      // 8*65536*16 B = 8 MB

    gs_prep<<<3, 256, 0, stream>>>(means, quats, scales, opac, rgbs, params);
    gs_composite<<<256*NQTR, dim3(64,4), 0, stream>>>(params, qpart);
    gs_combine<<<NPX/256, 256, 0, stream>>>(qpart, (float*)d_out);
}

// Round 5
// 100.108 us; speedup vs baseline: 1.2092x; 1.0336x over previous
//
#include <hip/hip_runtime.h>
#include <math.h>

#define HH 256
#define WW 256
#define NG 714
#define NROWS 768          // padded to 3x256 prep grid; pad rows always culled
#define NGP4 716           // s_tz padded for float4 rank loop
#define SEG 23             // rows per wave sub-segment (32 segs x 23 = 736 >= 714)
#define NQTR 8             // depth slices per tile (8 x 4 waves = 32 segments)
#define FOCALF 128.0f
#define EPS2D_F 0.3f
#define ALPHA_MIN_F (1.0f/255.0f)
#define CAM_T_F 8.0f
#define LOG2E_F 1.4426950408889634f
#define PR 12              // floats/row: [mx,my,A2n,B2n][C2n,K,cr,cg][cb,e,f,thr]
#define T_EPS 0.003f       // in-wave early-break bound (error <= eps per channel)
#define NPX 65536

// Kernel 1: projection + conic + stable depth rank + scatter into sorted rows.
// Conic stored NEGATED, prefolded with log2(e); K = log2(op) folded additively:
// sg = A2n*dx^2 + B2n*dx*dy + C2n*dy^2 + K  ->  alpha = exp2(sg) = op*exp(-sigma).
// Cull fields: e = C-B^2/4A, f = A-B^2/4C (positive conic, >=0);
// gaussian irrelevant for a box iff max(e*dymin^2, f*dxmin^2) > thr = log2(255)+K
// (then alpha < 1/255 for EVERY pixel in the box -> reference zeroes it: EXACT cull).
__global__ __launch_bounds__(256) void gs_prep(
    const float* __restrict__ means, const float* __restrict__ quats,
    const float* __restrict__ scales, const float* __restrict__ opacities,
    const float* __restrict__ rgbs, float* __restrict__ params)
{
    __shared__ float s_tz[NGP4];
    const int lane = threadIdx.x;
    const int i = blockIdx.x * 256 + lane;

    for (int j = lane; j < NGP4; j += 256)
        s_tz[j] = (j < NG) ? (means[3*j+2] + CAM_T_F) : INFINITY;
    __syncthreads();

    if (i >= NROWS) return;
    if (i >= NG) {                      // pad rows: always culled (0 > thr=-1)
        float4* row = (float4*)(params + i*PR);
        row[0] = make_float4(0.f,0.f,0.f,0.f);
        row[1] = make_float4(0.f,0.f,0.f,0.f);
        row[2] = make_float4(0.f,0.f,0.f,-1.f);
        return;
    }

    float m0 = means[i*3+0], m1 = means[i*3+1];
    float tz = s_tz[i];
    float qw = quats[i*4+0], qx = quats[i*4+1], qy = quats[i*4+2], qz = quats[i*4+3];
    float qn = rsqrtf(qw*qw + qx*qx + qy*qy + qz*qz);
    qw*=qn; qx*=qn; qy*=qn; qz*=qn;
    float sx = scales[i*3+0], sy = scales[i*3+1], sz = scales[i*3+2];
    float s0 = sx*sx, s1 = sy*sy, s2 = sz*sz;
    float R00 = 1.f-2.f*(qy*qy+qz*qz), R01 = 2.f*(qx*qy-qw*qz), R02 = 2.f*(qx*qz+qw*qy);
    float R10 = 2.f*(qx*qy+qw*qz),     R11 = 1.f-2.f*(qx*qx+qz*qz), R12 = 2.f*(qy*qz-qw*qx);
    float R20 = 2.f*(qx*qz-qw*qy),     R21 = 2.f*(qy*qz+qw*qx),     R22 = 1.f-2.f*(qx*qx+qy*qy);
    float S00 = R00*R00*s0 + R01*R01*s1 + R02*R02*s2;
    float S01 = R00*R10*s0 + R01*R11*s1 + R02*R12*s2;
    float S02 = R00*R20*s0 + R01*R21*s1 + R02*R22*s2;
    float S11 = R10*R10*s0 + R11*R11*s1 + R12*R12*s2;
    float S12 = R10*R20*s0 + R11*R21*s1 + R12*R22*s2;
    float S22 = R20*R20*s0 + R21*R21*s1 + R22*R22*s2;
    float inv = 1.f/tz;
    float mx = FOCALF*m0*inv + 0.5f*WW;
    float my = FOCALF*m1*inv + 0.5f*HH;
    float j0 = FOCALF*inv;
    float j2 = -FOCALF*m0*inv*inv;
    float j5 = -FOCALF*m1*inv*inv;
    float a = j0*j0*S00 + 2.f*j0*j2*S02 + j2*j2*S22 + EPS2D_F;
    float b = j0*(j0*S01 + j2*S12) + j5*(j0*S02 + j2*S22);
    float c = j0*j0*S11 + 2.f*j0*j5*S12 + j5*j5*S22 + EPS2D_F;
    float det = a*c - b*b;
    float idet = 1.f/det;
    float hA = 0.5f*c*idet*LOG2E_F;      // positive conic terms (log2-scaled)
    float Bc = -b*idet*LOG2E_F;
    float hC = 0.5f*a*idet*LOG2E_F;
    float e  = hC - Bc*Bc/(4.f*hA);      // min over dx of sigma' = e*dy^2
    float f  = hA - Bc*Bc/(4.f*hC);      // min over dy of sigma' = f*dx^2
    float op = 1.f/(1.f+__expf(-opacities[i]));
    float K  = log2f(op);                // folded into exponent
    float thr = log2f(255.f) + K;        // cull iff bound > thr
    float cr = 1.f/(1.f+__expf(-rgbs[i*3+0]));
    float cg = 1.f/(1.f+__expf(-rgbs[i*3+1]));
    float cb = 1.f/(1.f+__expf(-rgbs[i*3+2]));

    const float4* t4 = (const float4*)s_tz;
    int rank = 0;
    #pragma unroll 4
    for (int jj = 0; jj < NGP4/4; ++jj) {
        float4 v = t4[jj];
        int j = 4*jj;
        rank += (v.x < tz) || (v.x == tz && (j+0) < i);
        rank += (v.y < tz) || (v.y == tz && (j+1) < i);
        rank += (v.z < tz) || (v.z == tz && (j+2) < i);
        rank += (v.w < tz) || (v.w == tz && (j+3) < i);
    }

    float4* row = (float4*)(params + rank*PR);
    row[0] = make_float4(mx, my, -hA, -Bc);
    row[1] = make_float4(-hC, K, cr, cg);
    row[2] = make_float4(cb, e, f, thr);
}

// Kernel 2: compositing, block-level depth split for load balance.
// 2048 blocks = 256 tiles (16x16 px) x 8 depth eighths; 8/CU avg (round-3
// lesson: never 1 block/CU). Block = 4 waves = 4 sub-segments (23 rows).
// NEW (round-5): per-wave ballot PRE-PASS -- lanes 0..SEG-1 each cull-test one
// row of the wave's segment (2 float4 loads, once); __ballot -> uniform hit
// mask; main loop iterates ONLY set bits via __ffsll with a distance-2
// register pipeline over hit rows. Kills the 23-iteration cull scan whose
// prefetch stalls (~200cy L2 vs ~40cy of cover) dominated composite time
// (evidence: SEG 46->23 only gained 1.5us => scan overhead, not serial path).
// Evaluation set, order, and break semantics bit-identical to round-4.
__global__ __launch_bounds__(256, 4) void gs_composite(
    const float* __restrict__ params, float4* __restrict__ qpart)
{
    __shared__ float4 part[4][4][64];       // [wave][row k][tx] = 16 KB
    const int tx = threadIdx.x;             // 0..63
    const int wv = __builtin_amdgcn_readfirstlane((int)threadIdx.y);
    const int tile = blockIdx.x >> 3;
    const int qtr  = blockIdx.x & 7;
    const int x0 = (tile & 15) * 16;
    const int y0 = (tile >> 4) * 16;
    const float px   = (float)(x0 + (tx & 15)) + 0.5f;
    const float yb   = (float)(y0 + ((tx >> 4) << 2)) + 0.5f;   // row-group base
    const float xc   = (float)x0 + 8.0f;    // box center, half-span 7.5
    const float ycen = (float)y0 + 8.0f;
    const int n0 = (qtr*4 + wv) * SEG;      // wave's sub-segment start

    const float4* p4 = (const float4*)params;

    // Pre-pass: lane l cull-tests row n0+l (exact same predicate as before).
    unsigned long long mask;
    {
        bool h = false;
        if (tx < SEG) {
            const int r = n0 + tx;
            float4 r0 = p4[3*r];
            float4 r2 = p4[3*r+2];
            float dymin = fmaxf(fabsf(ycen - r0.y) - 7.5f, 0.f);
            float dxmin = fmaxf(fabsf(xc   - r0.x) - 7.5f, 0.f);
            float mm = fmaxf(r2.y*dymin*dymin, r2.z*dxmin*dxmin);
            h = !(mm > r2.w);               // pads: 0 > -1 -> culled
        }
        mask = __ballot(h);                 // uniform across the wave
    }

    float T0=1.f,r0=0.f,g0=0.f,bl0=0.f;
    float T1=1.f,r1=0.f,g1=0.f,bl1=0.f;
    float T2=1.f,r2=0.f,g2=0.f,bl2=0.f;
    float T3=1.f,r3=0.f,g3=0.f,bl3=0.f;

    // Hit-only main loop, distance-2 register pipeline through the mask.
    int ra = -1, rb = -1;
    float4 A0,A1,A2,B0,B1,B2;
    if (mask) { ra = n0 + (__ffsll(mask)-1); mask &= mask-1;
                A0=p4[3*ra]; A1=p4[3*ra+1]; A2=p4[3*ra+2]; }
    if (mask) { rb = n0 + (__ffsll(mask)-1); mask &= mask-1;
                B0=p4[3*rb]; B1=p4[3*rb+1]; B2=p4[3*rb+2]; }
    while (ra >= 0) {
        float4 C0,C1,C2; int rc = -1;
        if (mask) { rc = n0 + (__ffsll(mask)-1); mask &= mask-1;
                    C0=p4[3*rc]; C1=p4[3*rc+1]; C2=p4[3*rc+2]; }

        float dy0 = yb - A0.y;
        float dy1 = dy0 + 1.f, dy2 = dy0 + 2.f, dy3 = dy0 + 3.f;
        float dx  = px - A0.x;
        float axx = fmaf(A0.z*dx, dx, A1.y);    // A2n*dx^2 + K
        float bdx = A0.w*dx;

        float sg0 = fmaf(bdx, dy0, fmaf(A1.x*dy0, dy0, axx));
        float al0 = __builtin_amdgcn_exp2f(sg0);
        al0 = (al0 < ALPHA_MIN_F) ? 0.f : al0;
        float w0 = T0*al0; r0 += w0*A1.z; g0 += w0*A1.w; bl0 += w0*A2.x; T0 -= w0;

        float sg1 = fmaf(bdx, dy1, fmaf(A1.x*dy1, dy1, axx));
        float al1 = __builtin_amdgcn_exp2f(sg1);
        al1 = (al1 < ALPHA_MIN_F) ? 0.f : al1;
        float w1 = T1*al1; r1 += w1*A1.z; g1 += w1*A1.w; bl1 += w1*A2.x; T1 -= w1;

        float sg2 = fmaf(bdx, dy2, fmaf(A1.x*dy2, dy2, axx));
        float al2 = __builtin_amdgcn_exp2f(sg2);
        al2 = (al2 < ALPHA_MIN_F) ? 0.f : al2;
        float w2 = T2*al2; r2 += w2*A1.z; g2 += w2*A1.w; bl2 += w2*A2.x; T2 -= w2;

        float sg3 = fmaf(bdx, dy3, fmaf(A1.x*dy3, dy3, axx));
        float al3 = __builtin_amdgcn_exp2f(sg3);
        al3 = (al3 < ALPHA_MIN_F) ? 0.f : al3;
        float w3 = T3*al3; r3 += w3*A1.z; g3 += w3*A1.w; bl3 += w3*A2.x; T3 -= w3;

        // register-only early break (local T bounds true T from above)
        float tmax = fmaxf(fmaxf(T0,T1), fmaxf(T2,T3));
        if (__ballot(tmax > T_EPS) == 0ull) break;

        A0=B0; A1=B1; A2=B2; ra=rb;
        B0=C0; B1=C1; B2=C2; rb=rc;
    }

    part[wv][0][tx] = make_float4(r0,g0,bl0,T0);
    part[wv][1][tx] = make_float4(r1,g1,bl1,T1);
    part[wv][2][tx] = make_float4(r2,g2,bl2,T2);
    part[wv][3][tx] = make_float4(r3,g3,bl3,T3);
    __syncthreads();

    {   // wave k reduces pixel-row k of each thread's 4-row bundle, in depth order
        const int k = wv;
        float R=0.f,G=0.f,B=0.f,T=1.f;
        #pragma unroll
        for (int s = 0; s < 4; ++s) {
            float4 v = part[s][k][tx];
            R += T*v.x; G += T*v.y; B += T*v.z; T *= v.w;
        }
        const int y = y0 + ((tx >> 4) << 2) + k;
        const int x = x0 + (tx & 15);
        qpart[qtr*NPX + y*WW + x] = make_float4(R,G,B,T);
    }
}

// Kernel 3: fold the 8 depth-slice partials in order.
__global__ __launch_bounds__(256) void gs_combine(
    const float4* __restrict__ qpart, float* __restrict__ out)
{
    const int px = blockIdx.x*256 + threadIdx.x;
    float R=0.f, G=0.f, B=0.f, T=1.f;
    #pragma unroll
    for (int q = 0; q < NQTR; ++q) {
        float4 p = qpart[q*NPX + px];
        R += T*p.x; G += T*p.y; B += T*p.z; T *= p.w;
    }
    out[px*3+0] = R;
    out[px*3+1] = G;
    out[px*3+2] = B;
}

extern "C" void kernel_launch(void* const* d_in, const int* in_sizes, int n_in,
                              void* d_out, int out_size, void* d_ws, size_t ws_size,
                              hipStream_t stream) {
    // d_in: 0=coords (unused by reference), 1=means, 2=quats, 3=scales, 4=opacities, 5=rgbs
    const float* means  = (const float*)d_in[1];
    const float* quats  = (const float*)d_in[2];
    const float* scales = (const float*)d_in[3];
    const float* opac   = (const float*)d_in[4];
    const float* rgbs   = (const float*)d_in[5];

    char* ws = (char*)d_ws;
    float*  params = (float*)ws;                    // NROWS*PR floats = 36 KB
    float4* qpart  = (float4*)(ws + (64<<10));      // 8*65536*16 B = 8 MB

    gs_prep<<<3, 256, 0, stream>>>(means, quats, scales, opac, rgbs, params);
    gs_composite<<<256*NQTR, dim3(64,4), 0, stream>>>(params, qpart);
    gs_combine<<<NPX/256, 256, 0, stream>>>(qpart, (float*)d_out);
}